// Round 5
// baseline (438.760 us; speedup 1.0000x reference)
//
#include <hip/hip_runtime.h>
#include <math.h>
#include <float.h>
#include <limits.h>

#define BN      32768   // B*N query rows
#define D_IN    1024
#define E_DIM   128
#define CB_N    8192

typedef _Float16 f16x8 __attribute__((ext_vector_type(8)));
typedef _Float16 f16x4 __attribute__((ext_vector_type(4)));
typedef float    f32x4 __attribute__((ext_vector_type(4)));

// Workspace:
//   ph  : [CB_N/16][4][64][8] f16   2 MB  (ncb*256 hi, B-frag packed)
//   pl  : same                      2 MB
//   rph : [32*8][64][8] f16         0.25 MB (rp*64 hi, B-frag packed)
//   rpl : same                      0.25 MB

// ---------------------------------------------------------------------------
// Kernel 1: merged packs.
//  blocks [0,512):   codebook normalize (scale 256) + B-frag pack (validated)
//  blocks [512,576): rp*64 split pack, 4 waves/block, b=(blk-512)*4+w (validated)
// ---------------------------------------------------------------------------
__global__ __launch_bounds__(256) void pack_kernel(
    const float* __restrict__ cb, const float* __restrict__ rp,
    _Float16* __restrict__ ph, _Float16* __restrict__ pl,
    _Float16* __restrict__ rph, _Float16* __restrict__ rpl) {
    const int t = threadIdx.x;
    if (blockIdx.x < 512) {
        __shared__ float L[16][129];
        const int g = blockIdx.x;
        const int c = t >> 4, p = t & 15;
        const float4 v0 = *(const float4*)&cb[(size_t)(g * 16 + c) * E_DIM + p * 8];
        const float4 v1 = *(const float4*)&cb[(size_t)(g * 16 + c) * E_DIM + p * 8 + 4];
        float ss = v0.x * v0.x + v0.y * v0.y + v0.z * v0.z + v0.w * v0.w
                 + v1.x * v1.x + v1.y * v1.y + v1.z * v1.z + v1.w * v1.w;
#pragma unroll
        for (int m = 1; m < 16; m <<= 1) ss += __shfl_xor(ss, m);
        const float inv = 256.0f / fmaxf(sqrtf(ss), 1e-12f);

        L[c][p * 8 + 0] = v0.x * inv; L[c][p * 8 + 1] = v0.y * inv;
        L[c][p * 8 + 2] = v0.z * inv; L[c][p * 8 + 3] = v0.w * inv;
        L[c][p * 8 + 4] = v1.x * inv; L[c][p * 8 + 5] = v1.y * inv;
        L[c][p * 8 + 6] = v1.z * inv; L[c][p * 8 + 7] = v1.w * inv;
        __syncthreads();

        const int kb = t >> 6, lane = t & 63;
        const int quad = (lane >> 4), col = lane & 15;
        f16x8 h, l;
#pragma unroll
        for (int j = 0; j < 8; ++j) {
            const float v = L[col][kb * 32 + quad * 8 + j];
            const _Float16 hv = (_Float16)v;
            h[j] = hv;
            l[j] = (_Float16)(v - (float)hv);
        }
        const size_t off = ((size_t)(g * 4 + kb) * 64 + lane) * 8;
        *(f16x8*)&ph[off] = h;
        *(f16x8*)&pl[off] = l;
    } else {
        const int w = t >> 6, lane = t & 63;
        const int b = (blockIdx.x - 512) * 4 + w;      // 0..255
        const int kb = b >> 3, nt = b & 7;
        const int quad = lane >> 4, col = lane & 15;
        f16x8 h, l;
#pragma unroll
        for (int j = 0; j < 8; ++j) {
            const float v = rp[(size_t)(kb * 32 + quad * 8 + j) * E_DIM + nt * 16 + col] * 64.0f;
            const _Float16 hv = (_Float16)v;
            h[j] = hv;
            l[j] = (_Float16)(v - (float)hv);
        }
        const size_t off = ((size_t)b * 64 + lane) * 8;
        *(f16x8*)&rph[off] = h;
        *(f16x8*)&rpl[off] = l;
    }
}

// ---------------------------------------------------------------------------
// Kernel 2: FUSED proj + scores + argmax, 128 queries/block, grid 256 (1/CU).
// Phase 1: proj for 128 rows via f16-split MFMA (acc[8][2]).
// Handoff: 4 rounds x 32 queries through 16.9 KB LDS; wave i grabs its A-frags.
// Phase 2: B staged in LDS (32-code supertiles, 2x16KB dbuf, 1 barrier/iter),
//          all 4 waves consume the same stream -> codebook read ONCE per block.
// LDS: one 32 KB region aliased across phases (barrier-separated).
// ---------------------------------------------------------------------------
#define PAD_ROW 40    // phase-1 staging row stride (halfwords)
#define HPITCH  132   // handoff row pitch (dwords)

__global__ __launch_bounds__(256, 1) void fused_kernel(
    const float* __restrict__ x,
    const _Float16* __restrict__ rph, const _Float16* __restrict__ rpl,
    const _Float16* __restrict__ ph, const _Float16* __restrict__ pl,
    int* __restrict__ out) {
    __shared__ __align__(16) unsigned char smem[32768];
    _Float16* Ah = (_Float16*)smem;               // phase1: [128][40] 10.25 KB
    _Float16* Al = (_Float16*)(smem + 10240);     // phase1: 10.25 KB
    float*    Pq = (float*)smem;                  // handoff: [32][132] 16.9 KB
    _Float16* Bb = (_Float16*)smem;               // phase2: 2 x 16 KB dbuf

    const int tid  = threadIdx.x;
    const int lane = tid & 63;
    const int w    = tid >> 6;
    const int quad = lane >> 4, col = lane & 15;
    const int qb   = blockIdx.x * 128;

    // ======================= Phase 1: projection =======================
    const int srow = tid >> 1;          // 0..127
    const int scol = (tid & 1) * 16;    // 0 or 16

    f32x4 acc[8][2];
#pragma unroll
    for (int mt = 0; mt < 8; ++mt)
#pragma unroll
        for (int h = 0; h < 2; ++h) acc[mt][h] = (f32x4){0.f, 0.f, 0.f, 0.f};

    float4 pre[4];
#pragma unroll
    for (int c = 0; c < 4; ++c)
        pre[c] = *(const float4*)&x[(size_t)(qb + srow) * D_IN + scol + c * 4];

    for (int kb = 0; kb < 32; ++kb) {
#pragma unroll
        for (int c = 0; c < 4; ++c) {
            const float vv[4] = {pre[c].x, pre[c].y, pre[c].z, pre[c].w};
            f16x4 h4, l4;
#pragma unroll
            for (int j = 0; j < 4; ++j) {
                const float v = vv[j] * 512.0f;
                const _Float16 hv = (_Float16)v;
                h4[j] = hv;
                l4[j] = (_Float16)(v - (float)hv);
            }
            const int base = srow * PAD_ROW + scol + c * 4;
            *(f16x4*)&Ah[base] = h4;
            *(f16x4*)&Al[base] = l4;
        }
        __syncthreads();

        if (kb + 1 < 32) {
#pragma unroll
            for (int c = 0; c < 4; ++c)
                pre[c] = *(const float4*)&x[(size_t)(qb + srow) * D_IN + (kb + 1) * 32 + scol + c * 4];
        }

        f16x8 bh1[2], bl1[2];
#pragma unroll
        for (int h = 0; h < 2; ++h) {
            const int nt = w * 2 + h;
            const size_t off = ((size_t)(kb * 8 + nt) * 64 + lane) * 8;
            bh1[h] = *(const f16x8*)&rph[off];
            bl1[h] = *(const f16x8*)&rpl[off];
        }

        f16x8 ah1[8], al1[8];
#pragma unroll
        for (int mt = 0; mt < 8; ++mt) {
            const int base = (mt * 16 + col) * PAD_ROW + quad * 8;
            ah1[mt] = *(const f16x8*)&Ah[base];
            al1[mt] = *(const f16x8*)&Al[base];
        }

#pragma unroll
        for (int mt = 0; mt < 8; ++mt)
#pragma unroll
            for (int h = 0; h < 2; ++h)
                acc[mt][h] = __builtin_amdgcn_mfma_f32_16x16x32_f16(ah1[mt], bh1[h], acc[mt][h], 0, 0, 0);
#pragma unroll
        for (int mt = 0; mt < 8; ++mt)
#pragma unroll
            for (int h = 0; h < 2; ++h)
                acc[mt][h] = __builtin_amdgcn_mfma_f32_16x16x32_f16(ah1[mt], bl1[h], acc[mt][h], 0, 0, 0);
#pragma unroll
        for (int mt = 0; mt < 8; ++mt)
#pragma unroll
            for (int h = 0; h < 2; ++h)
                acc[mt][h] = __builtin_amdgcn_mfma_f32_16x16x32_f16(al1[mt], bh1[h], acc[mt][h], 0, 0, 0);

        __syncthreads();
    }

    // ======================= Handoff: C-layout -> A-frags =======================
    // Prefetch B supertile 0 early (global only, overlaps handoff).
    f16x8 stg[4];
#pragma unroll
    for (int r = 0; r < 4; ++r) {
        const int cc = w * 4 + r;
        const _Float16* src = (cc < 8) ? &ph[(size_t)0 * 4096 + cc * 512 + lane * 8]
                                       : &pl[(size_t)0 * 4096 + (cc - 8) * 512 + lane * 8];
        stg[r] = *(const f16x8*)src;
    }

    f16x8 ahF[2][4], alF[2][4];
#pragma unroll
    for (int i = 0; i < 4; ++i) {
        // all threads write rows [i*32, i*32+32): mt = 2i + m2
#pragma unroll
        for (int m2 = 0; m2 < 2; ++m2) {
            const int mt = i * 2 + m2;
#pragma unroll
            for (int h = 0; h < 2; ++h)
#pragma unroll
                for (int r = 0; r < 4; ++r)
                    Pq[(m2 * 16 + quad * 4 + r) * HPITCH + w * 32 + h * 16 + col]
                        = acc[mt][h][r] * (1.0f / 2048.0f);
        }
        __syncthreads();
        if (w == i) {
#pragma unroll
            for (int mt2 = 0; mt2 < 2; ++mt2)
#pragma unroll
                for (int kbb = 0; kbb < 4; ++kbb) {
                    const int base = (mt2 * 16 + col) * HPITCH + kbb * 32 + quad * 8;
                    const float4 v0 = *(const float4*)&Pq[base];
                    const float4 v1 = *(const float4*)&Pq[base + 4];
                    const float vv[8] = {v0.x, v0.y, v0.z, v0.w, v1.x, v1.y, v1.z, v1.w};
                    f16x8 hh, ll;
#pragma unroll
                    for (int j = 0; j < 8; ++j) {
                        const _Float16 hv = (_Float16)vv[j];
                        hh[j] = hv;
                        ll[j] = (_Float16)(vv[j] - (float)hv);
                    }
                    ahF[mt2][kbb] = hh;
                    alF[mt2][kbb] = ll;
                }
        }
        __syncthreads();
    }

    // ======================= Phase 2: scores + argmax =======================
    float bs[8];
    int   bi[8];
#pragma unroll
    for (int s = 0; s < 8; ++s) { bs[s] = -FLT_MAX; bi[s] = 0; }

    // write supertile 0 into buf 0
#pragma unroll
    for (int r = 0; r < 4; ++r) {
        const int cc = w * 4 + r;
        *(f16x8*)&Bb[cc * 512 + lane * 8] = stg[r];
    }
    __syncthreads();

    for (int t = 0; t < 256; ++t) {
        f16x8 nxt[4];
        if (t + 1 < 256) {
#pragma unroll
            for (int r = 0; r < 4; ++r) {
                const int cc = w * 4 + r;
                const _Float16* src = (cc < 8)
                    ? &ph[(size_t)(t + 1) * 4096 + cc * 512 + lane * 8]
                    : &pl[(size_t)(t + 1) * 4096 + (cc - 8) * 512 + lane * 8];
                nxt[r] = *(const f16x8*)src;
            }
        }

        const int bufo = (t & 1) * 8192;
#pragma unroll
        for (int ct = 0; ct < 2; ++ct) {
            f16x8 bh[4], bl[4];
#pragma unroll
            for (int kbb = 0; kbb < 4; ++kbb) {
                bh[kbb] = *(const f16x8*)&Bb[bufo + (ct * 4 + kbb) * 512 + lane * 8];
                bl[kbb] = *(const f16x8*)&Bb[bufo + 4096 + (ct * 4 + kbb) * 512 + lane * 8];
            }

            f32x4 s0 = (f32x4){0.f, 0.f, 0.f, 0.f};
            f32x4 s1 = (f32x4){0.f, 0.f, 0.f, 0.f};
#pragma unroll
            for (int kbb = 0; kbb < 4; ++kbb) {
                s0 = __builtin_amdgcn_mfma_f32_16x16x32_f16(ahF[0][kbb], bh[kbb], s0, 0, 0, 0);
                s1 = __builtin_amdgcn_mfma_f32_16x16x32_f16(ahF[1][kbb], bh[kbb], s1, 0, 0, 0);
            }
#pragma unroll
            for (int kbb = 0; kbb < 4; ++kbb) {
                s0 = __builtin_amdgcn_mfma_f32_16x16x32_f16(ahF[0][kbb], bl[kbb], s0, 0, 0, 0);
                s1 = __builtin_amdgcn_mfma_f32_16x16x32_f16(ahF[1][kbb], bl[kbb], s1, 0, 0, 0);
            }
#pragma unroll
            for (int kbb = 0; kbb < 4; ++kbb) {
                s0 = __builtin_amdgcn_mfma_f32_16x16x32_f16(alF[0][kbb], bh[kbb], s0, 0, 0, 0);
                s1 = __builtin_amdgcn_mfma_f32_16x16x32_f16(alF[1][kbb], bh[kbb], s1, 0, 0, 0);
            }

            const int code = (t * 2 + ct) * 16 + col;
#pragma unroll
            for (int r = 0; r < 4; ++r) {
                if (s0[r] > bs[r])     { bs[r] = s0[r];     bi[r] = code; }      // ascending: > keeps min idx
                if (s1[r] > bs[4 + r]) { bs[4 + r] = s1[r]; bi[4 + r] = code; }
            }
        }

        if (t + 1 < 256) {
#pragma unroll
            for (int r = 0; r < 4; ++r) {
                const int cc = w * 4 + r;
                *(f16x8*)&Bb[((t + 1) & 1) * 8192 + cc * 512 + lane * 8] = nxt[r];
            }
        }
        __syncthreads();
    }

    // 16-lane (code-column) reduction per query; min-index tie-break.
#pragma unroll
    for (int s = 0; s < 8; ++s) {
#pragma unroll
        for (int m = 1; m < 16; m <<= 1) {
            const float os = __shfl_xor(bs[s], m);
            const int   oi = __shfl_xor(bi[s], m);
            if (os > bs[s] || (os == bs[s] && oi < bi[s])) { bs[s] = os; bi[s] = oi; }
        }
    }

    if (col == 0) {
#pragma unroll
        for (int mt2 = 0; mt2 < 2; ++mt2)
#pragma unroll
            for (int r = 0; r < 4; ++r)
                out[qb + w * 32 + mt2 * 16 + quad * 4 + r] = bi[mt2 * 4 + r];
    }
}

// ---------------------------------------------------------------------------
extern "C" void kernel_launch(void* const* d_in, const int* in_sizes, int n_in,
                              void* d_out, int out_size, void* d_ws, size_t ws_size,
                              hipStream_t stream) {
    const float* x  = (const float*)d_in[0];   // [8,4096,1024]
    const float* rp = (const float*)d_in[1];   // [1024,128]
    const float* cb = (const float*)d_in[2];   // [8192,128]
    int* out = (int*)d_out;                    // [8,4096] int32

    _Float16* ph  = (_Float16*)d_ws;                         // 2 MB
    _Float16* pl  = ph  + (size_t)CB_N * E_DIM;              // 2 MB
    _Float16* rph = pl  + (size_t)CB_N * E_DIM;              // 256 KB
    _Float16* rpl = rph + (size_t)D_IN * E_DIM;              // 256 KB

    pack_kernel<<<576, 256, 0, stream>>>(cb, rp, ph, pl, rph, rpl);
    fused_kernel<<<BN / 128, 256, 0, stream>>>(x, rph, rpl, ph, pl, out);
}

// Round 6
// 399.879 us; speedup vs baseline: 1.0972x; 1.0972x over previous
//
#include <hip/hip_runtime.h>
#include <math.h>
#include <float.h>
#include <limits.h>

#define BN      32768   // B*N query rows
#define D_IN    1024
#define E_DIM   128
#define CB_N    8192

typedef _Float16 f16x8 __attribute__((ext_vector_type(8)));
typedef _Float16 f16x4 __attribute__((ext_vector_type(4)));
typedef float    f32x4 __attribute__((ext_vector_type(4)));

// Workspace:
//   ph  : [CB_N/16][4][64][8] f16   2 MB  (ncb*256 hi, B-frag packed)
//   pl  : same                      2 MB
//   rph : [32*8][64][8] f16         0.25 MB (rp*64 hi, B-frag packed)
//   rpl : same                      0.25 MB

// ---------------------------------------------------------------------------
// Kernel 1: merged packs (validated round 5).
// ---------------------------------------------------------------------------
__global__ __launch_bounds__(256) void pack_kernel(
    const float* __restrict__ cb, const float* __restrict__ rp,
    _Float16* __restrict__ ph, _Float16* __restrict__ pl,
    _Float16* __restrict__ rph, _Float16* __restrict__ rpl) {
    const int t = threadIdx.x;
    if (blockIdx.x < 512) {
        __shared__ float L[16][129];
        const int g = blockIdx.x;
        const int c = t >> 4, p = t & 15;
        const float4 v0 = *(const float4*)&cb[(size_t)(g * 16 + c) * E_DIM + p * 8];
        const float4 v1 = *(const float4*)&cb[(size_t)(g * 16 + c) * E_DIM + p * 8 + 4];
        float ss = v0.x * v0.x + v0.y * v0.y + v0.z * v0.z + v0.w * v0.w
                 + v1.x * v1.x + v1.y * v1.y + v1.z * v1.z + v1.w * v1.w;
#pragma unroll
        for (int m = 1; m < 16; m <<= 1) ss += __shfl_xor(ss, m);
        const float inv = 256.0f / fmaxf(sqrtf(ss), 1e-12f);

        L[c][p * 8 + 0] = v0.x * inv; L[c][p * 8 + 1] = v0.y * inv;
        L[c][p * 8 + 2] = v0.z * inv; L[c][p * 8 + 3] = v0.w * inv;
        L[c][p * 8 + 4] = v1.x * inv; L[c][p * 8 + 5] = v1.y * inv;
        L[c][p * 8 + 6] = v1.z * inv; L[c][p * 8 + 7] = v1.w * inv;
        __syncthreads();

        const int kb = t >> 6, lane = t & 63;
        const int quad = (lane >> 4), col = lane & 15;
        f16x8 h, l;
#pragma unroll
        for (int j = 0; j < 8; ++j) {
            const float v = L[col][kb * 32 + quad * 8 + j];
            const _Float16 hv = (_Float16)v;
            h[j] = hv;
            l[j] = (_Float16)(v - (float)hv);
        }
        const size_t off = ((size_t)(g * 4 + kb) * 64 + lane) * 8;
        *(f16x8*)&ph[off] = h;
        *(f16x8*)&pl[off] = l;
    } else {
        const int w = t >> 6, lane = t & 63;
        const int b = (blockIdx.x - 512) * 4 + w;      // 0..255
        const int kb = b >> 3, nt = b & 7;
        const int quad = lane >> 4, col = lane & 15;
        f16x8 h, l;
#pragma unroll
        for (int j = 0; j < 8; ++j) {
            const float v = rp[(size_t)(kb * 32 + quad * 8 + j) * E_DIM + nt * 16 + col] * 64.0f;
            const _Float16 hv = (_Float16)v;
            h[j] = hv;
            l[j] = (_Float16)(v - (float)hv);
        }
        const size_t off = ((size_t)b * 64 + lane) * 8;
        *(f16x8*)&rph[off] = h;
        *(f16x8*)&rpl[off] = l;
    }
}

// ---------------------------------------------------------------------------
// Kernel 2: FUSED proj + scores + argmax. 64 queries/block, grid 512 (2/CU).
// Phase 1: round-4 proj loop (validated) -> LDS P [64][132] f32.
// Phase 2: each wave owns ALL 64 queries (4 m-tiles = 4 independent MFMA
// chains) x a quarter of the codes; B-frags register double-buffered.
// ---------------------------------------------------------------------------
#define PAD_ROW 40    // phase-1 staging row stride (halfwords)
#define PPITCH  132   // P row pitch (dwords)

__global__ __launch_bounds__(256, 2) void fused_kernel(
    const float* __restrict__ x,
    const _Float16* __restrict__ rph, const _Float16* __restrict__ rpl,
    const _Float16* __restrict__ ph, const _Float16* __restrict__ pl,
    int* __restrict__ out) {
    __shared__ _Float16 Ah[64 * PAD_ROW];
    __shared__ _Float16 Al[64 * PAD_ROW];
    __shared__ float    P[64 * PPITCH];
    __shared__ float    ls[4][64];
    __shared__ int      li[4][64];

    const int tid  = threadIdx.x;
    const int lane = tid & 63;
    const int w    = tid >> 6;
    const int quad = lane >> 4, col = lane & 15;
    const int qb   = blockIdx.x * 64;

    // ======================= Phase 1: projection =======================
    const int srow = tid >> 3;        // 0..31
    const int skc  = (tid & 7) * 4;   // 0,4,..,28

    f32x4 acc[4][2];
#pragma unroll
    for (int mt = 0; mt < 4; ++mt)
#pragma unroll
        for (int h = 0; h < 2; ++h) acc[mt][h] = (f32x4){0.f, 0.f, 0.f, 0.f};

    float4 pre[2];
#pragma unroll
    for (int i = 0; i < 2; ++i)
        pre[i] = *(const float4*)&x[(size_t)(qb + srow + 32 * i) * D_IN + skc];

    for (int kb = 0; kb < 32; ++kb) {
#pragma unroll
        for (int i = 0; i < 2; ++i) {
            const float vv[4] = {pre[i].x, pre[i].y, pre[i].z, pre[i].w};
            f16x4 h4, l4;
#pragma unroll
            for (int j = 0; j < 4; ++j) {
                const float v = vv[j] * 512.0f;
                const _Float16 hv = (_Float16)v;
                h4[j] = hv;
                l4[j] = (_Float16)(v - (float)hv);
            }
            const int base = (srow + 32 * i) * PAD_ROW + skc;
            *(f16x4*)&Ah[base] = h4;
            *(f16x4*)&Al[base] = l4;
        }
        __syncthreads();

        if (kb + 1 < 32) {
#pragma unroll
            for (int i = 0; i < 2; ++i)
                pre[i] = *(const float4*)&x[(size_t)(qb + srow + 32 * i) * D_IN + (kb + 1) * 32 + skc];
        }

        f16x8 bh1[2], bl1[2];
#pragma unroll
        for (int h = 0; h < 2; ++h) {
            const int nt = w * 2 + h;
            const size_t off = ((size_t)(kb * 8 + nt) * 64 + lane) * 8;
            bh1[h] = *(const f16x8*)&rph[off];
            bl1[h] = *(const f16x8*)&rpl[off];
        }

        f16x8 ah1[4], al1[4];
#pragma unroll
        for (int mt = 0; mt < 4; ++mt) {
            const int base = (mt * 16 + col) * PAD_ROW + quad * 8;
            ah1[mt] = *(const f16x8*)&Ah[base];
            al1[mt] = *(const f16x8*)&Al[base];
        }

#pragma unroll
        for (int mt = 0; mt < 4; ++mt)
#pragma unroll
            for (int h = 0; h < 2; ++h)
                acc[mt][h] = __builtin_amdgcn_mfma_f32_16x16x32_f16(ah1[mt], bh1[h], acc[mt][h], 0, 0, 0);
#pragma unroll
        for (int mt = 0; mt < 4; ++mt)
#pragma unroll
            for (int h = 0; h < 2; ++h)
                acc[mt][h] = __builtin_amdgcn_mfma_f32_16x16x32_f16(ah1[mt], bl1[h], acc[mt][h], 0, 0, 0);
#pragma unroll
        for (int mt = 0; mt < 4; ++mt)
#pragma unroll
            for (int h = 0; h < 2; ++h)
                acc[mt][h] = __builtin_amdgcn_mfma_f32_16x16x32_f16(al1[mt], bh1[h], acc[mt][h], 0, 0, 0);

        __syncthreads();
    }

    // Write proj*16 (f32) to LDS [query][k].
#pragma unroll
    for (int mt = 0; mt < 4; ++mt)
#pragma unroll
        for (int h = 0; h < 2; ++h)
#pragma unroll
            for (int r = 0; r < 4; ++r)
                P[(mt * 16 + quad * 4 + r) * PPITCH + w * 32 + h * 16 + col]
                    = acc[mt][h][r] * (1.0f / 2048.0f);

    // Prefetch B tile 0 of this wave's code quarter (independent of LDS).
    const int g0 = w * 128;   // 128 16-code tiles per wave
    f16x8 bh[2][4], bl[2][4];
#pragma unroll
    for (int kb = 0; kb < 4; ++kb) {
        const size_t off = ((size_t)(g0 * 4 + kb) * 64 + lane) * 8;
        bh[0][kb] = *(const f16x8*)&ph[off];
        bl[0][kb] = *(const f16x8*)&pl[off];
    }
    __syncthreads();

    // ============ Handoff: every wave reads ALL 64 queries' A-frags ============
    f16x8 ahF[4][4], alF[4][4];
#pragma unroll
    for (int mt = 0; mt < 4; ++mt)
#pragma unroll
        for (int kbb = 0; kbb < 4; ++kbb) {
            const int base = (mt * 16 + col) * PPITCH + kbb * 32 + quad * 8;
            const float4 v0 = *(const float4*)&P[base];
            const float4 v1 = *(const float4*)&P[base + 4];
            const float vv[8] = {v0.x, v0.y, v0.z, v0.w, v1.x, v1.y, v1.z, v1.w};
            f16x8 hh, ll;
#pragma unroll
            for (int j = 0; j < 8; ++j) {
                const _Float16 hv = (_Float16)vv[j];
                hh[j] = hv;
                ll[j] = (_Float16)(vv[j] - (float)hv);
            }
            ahF[mt][kbb] = hh;
            alF[mt][kbb] = ll;
        }

    // ======================= Phase 2: scores + argmax =======================
    float bs[16];
    int   bi[16];
#pragma unroll
    for (int s = 0; s < 16; ++s) { bs[s] = -FLT_MAX; bi[s] = 0; }

#pragma unroll 2
    for (int t = 0; t < 128; ++t) {
        const int cur = t & 1, nxt = cur ^ 1;
        if (t + 1 < 128) {
            const int gn = g0 + t + 1;
#pragma unroll
            for (int kb = 0; kb < 4; ++kb) {
                const size_t off = ((size_t)(gn * 4 + kb) * 64 + lane) * 8;
                bh[nxt][kb] = *(const f16x8*)&ph[off];
                bl[nxt][kb] = *(const f16x8*)&pl[off];
            }
        }

        f32x4 sacc[4];
#pragma unroll
        for (int mt = 0; mt < 4; ++mt) sacc[mt] = (f32x4){0.f, 0.f, 0.f, 0.f};

        // kb-outer / mt-inner: 4 independent chains, dependent gap = 4 issues
#pragma unroll
        for (int kb = 0; kb < 4; ++kb)
#pragma unroll
            for (int mt = 0; mt < 4; ++mt)
                sacc[mt] = __builtin_amdgcn_mfma_f32_16x16x32_f16(ahF[mt][kb], bh[cur][kb], sacc[mt], 0, 0, 0);
#pragma unroll
        for (int kb = 0; kb < 4; ++kb)
#pragma unroll
            for (int mt = 0; mt < 4; ++mt)
                sacc[mt] = __builtin_amdgcn_mfma_f32_16x16x32_f16(ahF[mt][kb], bl[cur][kb], sacc[mt], 0, 0, 0);
#pragma unroll
        for (int kb = 0; kb < 4; ++kb)
#pragma unroll
            for (int mt = 0; mt < 4; ++mt)
                sacc[mt] = __builtin_amdgcn_mfma_f32_16x16x32_f16(alF[mt][kb], bh[cur][kb], sacc[mt], 0, 0, 0);

        const int code = (g0 + t) * 16 + col;
#pragma unroll
        for (int mt = 0; mt < 4; ++mt)
#pragma unroll
            for (int r = 0; r < 4; ++r) {
                const float v = sacc[mt][r];
                const int s = mt * 4 + r;
                if (v > bs[s]) { bs[s] = v; bi[s] = code; }  // ascending codes: > keeps min idx
            }
    }

    // Reduce the 16 code-columns per query (xor over low 4 lane bits).
#pragma unroll
    for (int s = 0; s < 16; ++s) {
#pragma unroll
        for (int m = 1; m < 16; m <<= 1) {
            const float os = __shfl_xor(bs[s], m);
            const int   oi = __shfl_xor(bi[s], m);
            if (os > bs[s] || (os == bs[s] && oi < bi[s])) { bs[s] = os; bi[s] = oi; }
        }
    }

    if (col == 0) {
#pragma unroll
        for (int mt = 0; mt < 4; ++mt)
#pragma unroll
            for (int r = 0; r < 4; ++r) {
                ls[w][mt * 16 + quad * 4 + r] = bs[mt * 4 + r];
                li[w][mt * 16 + quad * 4 + r] = bi[mt * 4 + r];
            }
    }
    __syncthreads();

    // 4-way cross-wave merge (ascending code ranges by w: > keeps min idx).
    if (tid < 64) {
        float s = ls[0][tid];
        int   i = li[0][tid];
#pragma unroll
        for (int ww = 1; ww < 4; ++ww) {
            const float os = ls[ww][tid];
            if (os > s) { s = os; i = li[ww][tid]; }
        }
        out[qb + tid] = i;
    }
}

// ---------------------------------------------------------------------------
extern "C" void kernel_launch(void* const* d_in, const int* in_sizes, int n_in,
                              void* d_out, int out_size, void* d_ws, size_t ws_size,
                              hipStream_t stream) {
    const float* x  = (const float*)d_in[0];   // [8,4096,1024]
    const float* rp = (const float*)d_in[1];   // [1024,128]
    const float* cb = (const float*)d_in[2];   // [8192,128]
    int* out = (int*)d_out;                    // [8,4096] int32

    _Float16* ph  = (_Float16*)d_ws;                         // 2 MB
    _Float16* pl  = ph  + (size_t)CB_N * E_DIM;              // 2 MB
    _Float16* rph = pl  + (size_t)CB_N * E_DIM;              // 256 KB
    _Float16* rpl = rph + (size_t)D_IN * E_DIM;              // 256 KB

    pack_kernel<<<576, 256, 0, stream>>>(cb, rp, ph, pl, rph, rpl);
    fused_kernel<<<BN / 64, 256, 0, stream>>>(x, rph, rpl, ph, pl, out);
}